// Round 1
// baseline (135.827 us; speedup 1.0000x reference)
//
#include <hip/hip_runtime.h>
#include <math.h>

#define N_ATOMS   1500
#define NODE_DIM  128
#define HIDDEN    64
#define SPH_DIM   480
#define OFF0      128
#define MUL1E     64
#define HID1E     32
#define NUM_BASIS 20
#define NEDGE     (N_ATOMS * N_ATOMS)          // 2,250,000
#define OUT_F4    (NEDGE * 9 / 4)              // 5,062,500 float4s

__device__ __forceinline__ float wave_reduce_sum64(float v) {
#pragma unroll
    for (int m = 1; m <= 32; m <<= 1) v += __shfl_xor(v, m, 64);
    return v;
}
__device__ __forceinline__ float half_reduce_sum32(float v) {
#pragma unroll
    for (int m = 1; m <= 16; m <<= 1) v += __shfl_xor(v, m, 64);
    return v;
}

// Phase 1: one wave per node. Computes
//   a[n] = perm(sph_mlp_i(n)) * (1 + scalar_mlp_i(n))
//   b[n] = perm(sph_mlp_j(n)) * (1 + scalar_mlp_j(n))
__global__ __launch_bounds__(64) void node_precompute(
    const float* __restrict__ xs,   const float* __restrict__ xsph,
    const float* __restrict__ Wsi1, const float* __restrict__ Wsi2,
    const float* __restrict__ Wsj1, const float* __restrict__ Wsj2,
    const float* __restrict__ Wpi1, const float* __restrict__ Wpi2,
    const float* __restrict__ Wpj1, const float* __restrict__ Wpj2,
    float* __restrict__ a, float* __restrict__ b) {
    const int n = blockIdx.x;
    const int lane = threadIdx.x;

    // ---- scalar MLPs: silu(x @ W1) @ W2, lane = hidden unit ----
    const float* xr = xs + n * NODE_DIM;
    float zi = 0.f, zj = 0.f;
#pragma unroll 8
    for (int k = 0; k < NODE_DIM; ++k) {
        const float xv = xr[k];                 // broadcast
        zi += xv * Wsi1[k * HIDDEN + lane];     // coalesced
        zj += xv * Wsj1[k * HIDDEN + lane];
    }
    // silu(z) = z * sigmoid(z); safe at |z| large (inf -> 0 limit, no NaN)
    const float pi = zi / (1.f + __expf(-zi)) * Wsi2[lane];
    const float pj = zj / (1.f + __expf(-zj)) * Wsj2[lane];
    const float s_i = wave_reduce_sum64(pi);
    const float s_j = wave_reduce_sum64(pj);

    // ---- spherical 1e MLPs: lanes 0..31 -> Wpi, lanes 32..63 -> Wpj ----
    const int hh = lane & 31;
    const int which = lane >> 5;
    const float* W1 = which ? Wpj1 : Wpi1;      // [64,32]
    const float* W2 = which ? Wpj2 : Wpi2;      // [32,1]
    const float* vr = xsph + n * SPH_DIM + OFF0;
    float a0 = 0.f, a1 = 0.f, a2 = 0.f;
#pragma unroll 4
    for (int m = 0; m < MUL1E; ++m) {
        const float w = W1[m * HID1E + hh];
        a0 += vr[m * 3 + 0] * w;
        a1 += vr[m * 3 + 1] * w;
        a2 += vr[m * 3 + 2] * w;
    }
    a0 *= 0.125f; a1 *= 0.125f; a2 *= 0.125f;   // / sqrt(64)
    const float nrm = sqrtf(a0 * a0 + a1 * a1 + a2 * a2);
    const float gate = 1.f / (1.f + __expf(-nrm));
    const float w2 = W2[hh] * gate * 0.17677669529663687f;  // / sqrt(32)
    const float o0 = half_reduce_sum32(a0 * w2);
    const float o1 = half_reduce_sum32(a1 * w2);
    const float o2 = half_reduce_sum32(a2 * w2);
    // e3nn 1e (y,z,x) -> (x,y,z): result = (o2, o0, o1)
    if (lane == 0) {
        const float s = 1.f + s_i;
        a[n * 3 + 0] = o2 * s; a[n * 3 + 1] = o0 * s; a[n * 3 + 2] = o1 * s;
    } else if (lane == 32) {
        const float s = 1.f + s_j;
        b[n * 3 + 0] = o2 * s; b[n * 3 + 1] = o0 * s; b[n * 3 + 2] = o1 * s;
    }
}

// Phase 2: one thread per edge e = i*N + j.
//   out[e][r][c] = 0.5 * fc(d_ij) * (a_i[r]*b_j[c] + b_i[r]*a_j[c])
// LDS wave-transpose so global stores are coalesced dwordx4.
__global__ __launch_bounds__(256) void edge_kernel(
    const float* __restrict__ coord, const float* __restrict__ Wrbf,
    const float* __restrict__ a, const float* __restrict__ b,
    float* __restrict__ out) {
    __shared__ float sm[256 * 9];
    const int lane = threadIdx.x & 63;
    const int wid  = threadIdx.x >> 6;
    const int e = blockIdx.x * 256 + threadIdx.x;
    const int ee = (e < NEDGE) ? e : 0;
    const int i = ee / N_ATOMS;                 // magic-mul division
    const int j = ee - i * N_ATOMS;

    const float ai0 = a[i * 3], ai1 = a[i * 3 + 1], ai2 = a[i * 3 + 2];
    const float bi0 = b[i * 3], bi1 = b[i * 3 + 1], bi2 = b[i * 3 + 2];
    const float aj0 = a[j * 3], aj1 = a[j * 3 + 1], aj2 = a[j * 3 + 2];
    const float bj0 = b[j * 3], bj1 = b[j * 3 + 1], bj2 = b[j * 3 + 2];
    const float dx = coord[i * 3 + 0] - coord[j * 3 + 0];
    const float dy = coord[i * 3 + 1] - coord[j * 3 + 1];
    const float dz = coord[i * 3 + 2] - coord[j * 3 + 2];
    const float d = sqrtf(dx * dx + dy * dy + dz * dz);

    // fc = sum_k Wrbf[k] * exp(coeff * (d - o_k)^2); coeff = -0.5/(5/19)^2 = -7.22
    float fc = 0.f;
#pragma unroll
    for (int k = 0; k < NUM_BASIS; ++k) {
        const float o = (float)(5.0 * k / 19.0);
        const float t = d - o;
        fc += Wrbf[k] * __expf(-7.22f * (t * t));
    }
    fc *= 0.5f;

    float c[9];
    c[0] = fc * (ai0 * bj0 + bi0 * aj0);
    c[1] = fc * (ai0 * bj1 + bi0 * aj1);
    c[2] = fc * (ai0 * bj2 + bi0 * aj2);
    c[3] = fc * (ai1 * bj0 + bi1 * aj0);
    c[4] = fc * (ai1 * bj1 + bi1 * aj1);
    c[5] = fc * (ai1 * bj2 + bi1 * aj2);
    c[6] = fc * (ai2 * bj0 + bi2 * aj0);
    c[7] = fc * (ai2 * bj1 + bi2 * aj1);
    c[8] = fc * (ai2 * bj2 + bi2 * aj2);

    // stage edge-major in LDS (stride 9 -> 2-way bank alias, free)
#pragma unroll
    for (int t = 0; t < 9; ++t) sm[wid * 576 + lane * 9 + t] = c[t];
    __syncthreads();

    // coalesced float4 stores: wave region = 576 floats = 144 float4
    const float4* sm4 = (const float4*)sm;
    float4* out4 = (float4*)out;
    const int region4 = blockIdx.x * 576 + wid * 144;
#pragma unroll
    for (int t = lane; t < 144; t += 64) {
        const int g4 = region4 + t;
        if (g4 < OUT_F4) out4[g4] = sm4[wid * 144 + t];
    }
}

extern "C" void kernel_launch(void* const* d_in, const int* in_sizes, int n_in,
                              void* d_out, int out_size, void* d_ws, size_t ws_size,
                              hipStream_t stream) {
    const float* x_scalar = (const float*)d_in[0];
    const float* x_sph    = (const float*)d_in[1];
    const float* coord    = (const float*)d_in[2];
    // d_in[3] = fc_edge_index (int32) — known i-major full graph, unused
    const float* Wsi1 = (const float*)d_in[4];
    const float* Wsi2 = (const float*)d_in[5];
    const float* Wsj1 = (const float*)d_in[6];
    const float* Wsj2 = (const float*)d_in[7];
    const float* Wpi1 = (const float*)d_in[8];
    const float* Wpi2 = (const float*)d_in[9];
    const float* Wpj1 = (const float*)d_in[10];
    const float* Wpj2 = (const float*)d_in[11];
    const float* Wrbf = (const float*)d_in[12];
    float* out = (float*)d_out;

    float* a = (float*)d_ws;             // [N,3]
    float* b = a + 3 * N_ATOMS;          // [N,3]

    node_precompute<<<N_ATOMS, 64, 0, stream>>>(
        x_scalar, x_sph, Wsi1, Wsi2, Wsj1, Wsj2,
        Wpi1, Wpi2, Wpj1, Wpj2, a, b);

    const int nblk = (NEDGE + 255) / 256;   // 8790
    edge_kernel<<<nblk, 256, 0, stream>>>(coord, Wrbf, a, b, out);
}